// Round 1
// baseline (20463.773 us; speedup 1.0000x reference)
//
#include <hip/hip_runtime.h>
#include <cstdint>
#include <cstddef>

// ---------------------------------------------------------------------------
// PurifiedVAE: bidirectional GRU encoder (512 steps) -> mu/var heads -> rsample
//              -> GRU decoder with teacher forcing (512 steps) + sigmoid head.
// Strategy: one kernel launch per GRU step (stream ordering = global barrier).
// Recurrent matmul h@Whh^T done in f16 MFMA (16x16x32) with fp32 h master.
// x-projection, biases, and decoder z-projection folded into extended-K
// fp16 weight matrices prepared once per call.
// ---------------------------------------------------------------------------

typedef _Float16 f16;
typedef _Float16 f16x8 __attribute__((ext_vector_type(8)));
typedef float f32x4 __attribute__((ext_vector_type(4)));

#define NB 256
#define NT 512
#define NI 12
#define NH 1024
#define NZ 128
#define NG 3072
#define KE_ENC 1056   // 1024 + 32 ext (x,1,pad)
#define KE_DEC 1184   // 1024 + 160 ext (x,1,pad,z128)
#define XK_ENC 32
#define XK_DEC 160

// ---- workspace layout (bytes) ----
#define SZ_WM_ENC ((size_t)NG * KE_ENC * 2)
#define SZ_WM_DEC ((size_t)NG * KE_DEC * 2)
#define SZ_WN_ENC ((size_t)NH * XK_ENC * 2)
#define SZ_WN_DEC ((size_t)NH * XK_DEC * 2)
#define SZ_WOUT   ((size_t)16 * KE_ENC * 2)
#define SZ_H32    ((size_t)NB * NH * 4)
#define SZ_H16    ((size_t)NB * NH * 2)
#define OFF_WMF  ((size_t)0)
#define OFF_WMB  (OFF_WMF + SZ_WM_ENC)
#define OFF_WMD  (OFF_WMB + SZ_WM_ENC)
#define OFF_WNF  (OFF_WMD + SZ_WM_DEC)
#define OFF_WNB  (OFF_WNF + SZ_WN_ENC)
#define OFF_WND  (OFF_WNB + SZ_WN_ENC)
#define OFF_WOUT (OFF_WND + SZ_WN_DEC)
#define OFF_H32  (OFF_WOUT + SZ_WOUT)
#define OFF_H16  (OFF_H32 + 6 * SZ_H32)
#define OFF_Z32  (OFF_H16 + 6 * SZ_H16)
#define OFF_Z16  (OFF_Z32 + (size_t)NB * NZ * 4)
#define WS_NEEDED (OFF_Z16 + (size_t)NB * NZ * 2)

// d_out element offsets (fp32): recon [256,512,12], mean [256,128], stddev [256,128]
#define OUT_MEAN (NB * NT * NI)
#define OUT_STD  (OUT_MEAN + NB * NZ)

// ---------------------------------------------------------------------------
// prep: build fp16 extended weight matrices, zero initial h buffers.
// Extended layout per row c (output gate-column):
//   k<1024          : W_hh[c][k]
//   k=1024+e, e<12  : W_ih[c][e]           (zero for n-gate rows: i_n kept separate)
//   e==12           : bias  (r,z rows: b_ih+b_hh ; n rows: b_hh only)
//   13<=e<32        : 0
//   e>=32 (dec only): Wc_ih[c][12+e-32]    (z part; zero for n rows)
// WN (gi_n rows, j=0..1023 -> c=2048+j): [W_ih_n(12) | b_ih_n | 0 | z-part(dec)]
// WOUT: rows i<12: [W_out[i][k<1024] | 0.. | b_out at e==12 | 0..]
// ---------------------------------------------------------------------------
__global__ __launch_bounds__(256) void prep_kernel(
    const float* __restrict__ Whhf, const float* __restrict__ Wihf,
    const float* __restrict__ bihf, const float* __restrict__ bhhf,
    const float* __restrict__ Whhb, const float* __restrict__ Wihb,
    const float* __restrict__ bihb, const float* __restrict__ bhhb,
    const float* __restrict__ Wchh, const float* __restrict__ Wcih,
    const float* __restrict__ bcih, const float* __restrict__ bchh,
    const float* __restrict__ Wo,   const float* __restrict__ bo,
    f16* __restrict__ wmf, f16* __restrict__ wmb, f16* __restrict__ wmd,
    f16* __restrict__ wnf, f16* __restrict__ wnb, f16* __restrict__ wnd,
    f16* __restrict__ wout,
    float* __restrict__ h32f0, float* __restrict__ h32b0,
    f16* __restrict__ h16f0, f16* __restrict__ h16b0)
{
    const int gsz = gridDim.x * blockDim.x;
    const int gid = blockIdx.x * blockDim.x + threadIdx.x;

    // encoder main (f and b together)
    for (int idx = gid; idx < NG * KE_ENC; idx += gsz) {
        const int c = idx / KE_ENC, k = idx - c * KE_ENC;
        float vf, vb;
        if (k < NH) { vf = Whhf[c * NH + k]; vb = Whhb[c * NH + k]; }
        else {
            const int e = k - NH;
            if (c < 2 * NH) {
                if (e < 12)       { vf = Wihf[c * 12 + e]; vb = Wihb[c * 12 + e]; }
                else if (e == 12) { vf = bihf[c] + bhhf[c]; vb = bihb[c] + bhhb[c]; }
                else              { vf = 0.f; vb = 0.f; }
            } else {
                vf = (e == 12) ? bhhf[c] : 0.f;
                vb = (e == 12) ? bhhb[c] : 0.f;
            }
        }
        wmf[idx] = (f16)vf; wmb[idx] = (f16)vb;
    }
    // decoder main
    for (int idx = gid; idx < NG * KE_DEC; idx += gsz) {
        const int c = idx / KE_DEC, k = idx - c * KE_DEC;
        float v;
        if (k < NH) v = Wchh[c * NH + k];
        else {
            const int e = k - NH;
            if (c < 2 * NH) {
                if (e < 12)       v = Wcih[c * 140 + e];
                else if (e == 12) v = bcih[c] + bchh[c];
                else if (e < 32)  v = 0.f;
                else              v = Wcih[c * 140 + 12 + (e - 32)];
            } else v = (e == 12) ? bchh[c] : 0.f;
        }
        wmd[idx] = (f16)v;
    }
    // encoder gi_n rows
    for (int idx = gid; idx < NH * XK_ENC; idx += gsz) {
        const int j = idx >> 5, e = idx & 31;
        const int c = 2 * NH + j;
        float vf, vb;
        if (e < 12)       { vf = Wihf[c * 12 + e]; vb = Wihb[c * 12 + e]; }
        else if (e == 12) { vf = bihf[c]; vb = bihb[c]; }
        else              { vf = 0.f; vb = 0.f; }
        wnf[idx] = (f16)vf; wnb[idx] = (f16)vb;
    }
    // decoder gi_n rows
    for (int idx = gid; idx < NH * XK_DEC; idx += gsz) {
        const int j = idx / XK_DEC, e = idx - j * XK_DEC;
        const int c = 2 * NH + j;
        float v;
        if (e < 12)       v = Wcih[c * 140 + e];
        else if (e == 12) v = bcih[c];
        else if (e < 32)  v = 0.f;
        else              v = Wcih[c * 140 + 12 + (e - 32)];
        wnd[idx] = (f16)v;
    }
    // out head
    for (int idx = gid; idx < 16 * KE_ENC; idx += gsz) {
        const int i = idx / KE_ENC, k = idx - i * KE_ENC;
        float v = 0.f;
        if (i < 12) {
            if (k < NH) v = Wo[i * NH + k];
            else if (k == NH + 12) v = bo[i];
        }
        wout[idx] = (f16)v;
    }
    // zero initial encoder h
    for (int idx = gid; idx < NB * NH; idx += gsz) {
        h32f0[idx] = 0.f; h32b0[idx] = 0.f;
        h16f0[idx] = (f16)0.f; h16b0[idx] = (f16)0.f;
    }
}

// ---------------------------------------------------------------------------
// gru_step: one recurrence step.
// mode 0: encoder (grid 256; blocks 0..127 = fwd, 128..255 = bwd)
// mode 1: decoder (grid 128) -- also emits out_{t-1} (ji==0 blocks)
// mode 2: tail    (grid 4, widx = bid*32) -- emits out_511 only (t=512)
// WG tile: 64 rows x 96 cols (= {r,z,n} gates of a 32-wide hidden slice).
// Waves m-split (16 rows each). B staged via LDS (stride 72 halves,
// conflict-free); A-fragments loaded directly from global h16.
// acc[0..1]=r (ext-merged), acc[2..3]=z, acc[4..5]=gh_n(+b_hh), acc[6..7]=gi_n,
// acc[8]=out head.
// ---------------------------------------------------------------------------
__global__ __launch_bounds__(256) void gru_step(
    const float* __restrict__ x,
    const f16* __restrict__ wmA, const f16* __restrict__ wnA,
    const f16* __restrict__ h16inA, const float* __restrict__ h32inA,
    f16* __restrict__ h16outA, float* __restrict__ h32outA,
    const f16* __restrict__ wmB, const f16* __restrict__ wnB,
    const f16* __restrict__ h16inB, const float* __restrict__ h32inB,
    f16* __restrict__ h16outB, float* __restrict__ h32outB,
    const f16* __restrict__ wout, const f16* __restrict__ z16,
    float* __restrict__ dout,
    const int t, const int mode, const int KE, const int XK)
{
    extern __shared__ f16 sm[];
    const int XKP = XK + 8;
    f16* Bs = sm;                    // [2][96*72] main K staging (double-buffered)
    f16* Bx = sm + 2 * 96 * 72;      // [144*40]   ext-chunk staging
    f16* Zx = Bx + 144 * 40;         // [64*XKP]   A-ext rows

    const int tid = threadIdx.x;
    int bid = blockIdx.x;
    int dir = 0;
    if (mode == 0 && bid >= 128) { dir = 1; bid -= 128; }
    const int widx = (mode == 2) ? (bid << 5) : bid;
    const int mi = widx >> 5, ji = widx & 31;
    const int m0 = mi << 6, j0 = ji << 5;
    const bool outhead = (mode != 0) && (ji == 0);

    const f16*   wm     = dir ? wmB : wmA;
    const f16*   wn     = dir ? wnB : wnA;
    const f16*   h16in  = dir ? h16inB : h16inA;
    const float* h32in  = dir ? h32inB : h32inA;
    f16*         h16out = dir ? h16outB : h16outA;
    float*       h32out = dir ? h32outB : h32outA;

    // ---- stage A-ext rows: [x(12) | 1 | 0.. | z(128, dec)] as f16 ----
    {
        const int rl = tid >> 2;          // 64 rows, 4 threads/row
        const int seg = XK >> 2;
        const int e0 = (tid & 3) * seg;
        const int b = m0 + rl;
        for (int e = e0; e < e0 + seg; ++e) {
            f16 hv;
            if (e < 12) {
                float v;
                if (mode != 0 && t == 0) v = (e == 11) ? 1.0f : 0.0f;
                else {
                    const int tx = (mode == 0) ? (dir ? (NT - 1 - t) : t) : (t - 1);
                    v = x[((size_t)b * NT + tx) * NI + e];
                }
                hv = (f16)v;
            } else if (e == 12) hv = (f16)1.0f;
            else if (e < 32)    hv = (f16)0.0f;
            else                hv = z16[b * NZ + (e - 32)];
            Zx[rl * XKP + e] = hv;
        }
    }

    // ---- Bs staging geometry: 96 rows x 8 units (of 8 halves) per stage ----
    const f16* wsrc0; const f16* wsrc1; const f16* wsrc2;
    int sdst0, sdst1, sdst2;
    {
        int u = tid;
        int row = u >> 3, cu = u & 7;
        int c = ((row >> 5) << 10) + j0 + (row & 31);
        wsrc0 = wm + (size_t)c * KE + cu * 8; sdst0 = row * 72 + cu * 8;
        u = tid + 256; row = u >> 3; cu = u & 7;
        c = ((row >> 5) << 10) + j0 + (row & 31);
        wsrc1 = wm + (size_t)c * KE + cu * 8; sdst1 = row * 72 + cu * 8;
        u = tid + 512; row = u >> 3; cu = u & 7;
        c = ((row >> 5) << 10) + j0 + (row & 31);
        wsrc2 = wm + (size_t)c * KE + cu * 8; sdst2 = row * 72 + cu * 8;
    }

    const int w = tid >> 6, lane = tid & 63;
    const int lr = lane & 15, quad = lane >> 4;
    const int r0 = m0 + (w << 4);
    const int k8 = quad * 8;
    const f16* hAp   = h16in + (size_t)(r0 + lr) * NH + k8;
    const f16* woutp = wout + (size_t)lr * KE_ENC + k8;

    f32x4 acc[9];
#pragma unroll
    for (int i = 0; i < 9; ++i) { f32x4 zv = {0.f, 0.f, 0.f, 0.f}; acc[i] = zv; }

    uint4 breg0, breg1, breg2;
#define LOAD_STAGE(s) do { \
    breg0 = *(const uint4*)(wsrc0 + (s) * 64); \
    breg1 = *(const uint4*)(wsrc1 + (s) * 64); \
    breg2 = *(const uint4*)(wsrc2 + (s) * 64); } while (0)
#define STORE_STAGE(s) do { \
    f16* bb_ = Bs + ((s) & 1) * (96 * 72); \
    *(uint4*)(bb_ + sdst0) = breg0; \
    *(uint4*)(bb_ + sdst1) = breg1; \
    *(uint4*)(bb_ + sdst2) = breg2; } while (0)

    LOAD_STAGE(0);
    __syncthreads();          // Zx complete; Bs[0] about to be written
    STORE_STAGE(0);
    LOAD_STAGE(1);
    __syncthreads();

    f16x8 a0 = *(const f16x8*)(hAp);
    f16x8 a1 = *(const f16x8*)(hAp + 32);

    for (int s = 0; s < 16; ++s) {
        const f16* bb = Bs + (s & 1) * (96 * 72);
        f16x8 na0, na1;
        if (s < 15) {
            na0 = *(const f16x8*)(hAp + (s + 1) * 64);
            na1 = *(const f16x8*)(hAp + (s + 1) * 64 + 32);
        }
        // chunk 0
#pragma unroll
        for (int nt = 0; nt < 6; ++nt) {
            f16x8 bf = *(const f16x8*)(bb + (nt * 16 + lr) * 72 + k8);
            acc[nt] = __builtin_amdgcn_mfma_f32_16x16x32_f16(a0, bf, acc[nt], 0, 0, 0);
        }
        if (outhead) {
            f16x8 bf = *(const f16x8*)(woutp + s * 64);
            acc[8] = __builtin_amdgcn_mfma_f32_16x16x32_f16(a0, bf, acc[8], 0, 0, 0);
        }
        // chunk 1
#pragma unroll
        for (int nt = 0; nt < 6; ++nt) {
            f16x8 bf = *(const f16x8*)(bb + (nt * 16 + lr) * 72 + 32 + k8);
            acc[nt] = __builtin_amdgcn_mfma_f32_16x16x32_f16(a1, bf, acc[nt], 0, 0, 0);
        }
        if (outhead) {
            f16x8 bf = *(const f16x8*)(woutp + s * 64 + 32);
            acc[8] = __builtin_amdgcn_mfma_f32_16x16x32_f16(a1, bf, acc[8], 0, 0, 0);
        }
        a0 = na0; a1 = na1;
        if (s < 15) {
            __syncthreads();
            STORE_STAGE(s + 1);
            if (s < 14) LOAD_STAGE(s + 2);
            __syncthreads();
        }
    }

    // ---- ext-K chunks (x / bias / z region) ----
    const int nec = XK >> 5;
    for (int ce = 0; ce < nec; ++ce) {
        __syncthreads();
        for (int u = tid; u < 144 * 4; u += 256) {
            const int row = u >> 2, cu = u & 3;
            const int e0 = ce * 32 + cu * 8;
            uint4 v = make_uint4(0u, 0u, 0u, 0u);
            if (row < 96) {
                const int c = ((row >> 5) << 10) + j0 + (row & 31);
                v = *(const uint4*)(wm + (size_t)c * KE + NH + e0);
            } else if (row < 128) {
                const int j = j0 + (row - 96);
                v = *(const uint4*)(wn + (size_t)j * XK + e0);
            } else if (outhead && e0 < 32) {
                v = *(const uint4*)(wout + (size_t)(row - 128) * KE_ENC + NH + e0);
            }
            *(uint4*)(Bx + row * 40 + cu * 8) = v;
        }
        __syncthreads();
        f16x8 az = *(const f16x8*)(Zx + (size_t)((w << 4) + lr) * XKP + ce * 32 + k8);
#pragma unroll
        for (int nt = 0; nt < 6; ++nt) {
            f16x8 bf = *(const f16x8*)(Bx + (nt * 16 + lr) * 40 + k8);
            acc[nt] = __builtin_amdgcn_mfma_f32_16x16x32_f16(az, bf, acc[nt], 0, 0, 0);
        }
#pragma unroll
        for (int jt = 0; jt < 2; ++jt) {
            f16x8 bf = *(const f16x8*)(Bx + (96 + jt * 16 + lr) * 40 + k8);
            acc[6 + jt] = __builtin_amdgcn_mfma_f32_16x16x32_f16(az, bf, acc[6 + jt], 0, 0, 0);
        }
        if (outhead) {
            f16x8 bf = *(const f16x8*)(Bx + (128 + lr) * 40 + k8);
            acc[8] = __builtin_amdgcn_mfma_f32_16x16x32_f16(az, bf, acc[8], 0, 0, 0);
        }
    }

    // ---- gate combine + h update (fp32) ----
#pragma unroll
    for (int jt = 0; jt < 2; ++jt) {
        const int j = j0 + jt * 16 + lr;
#pragma unroll
        for (int r = 0; r < 4; ++r) {
            const int row = r0 + quad * 4 + r;
            const float rr  = acc[jt][r];
            const float zz  = acc[2 + jt][r];
            const float ghn = acc[4 + jt][r];
            const float gin = acc[6 + jt][r];
            const float rg = 1.f / (1.f + __expf(-rr));
            const float zg = 1.f / (1.f + __expf(-zz));
            const float nv = gin + rg * ghn;
            const float e2 = __expf(2.f * nv);
            const float th = 1.f - 2.f / (e2 + 1.f);   // tanh, inf-safe
            const float hp = h32in[(size_t)row * NH + j];
            const float hn = (1.f - zg) * th + zg * hp;
            h32out[(size_t)row * NH + j] = hn;
            h16out[(size_t)row * NH + j] = (f16)hn;
        }
    }
    // ---- decoder output head: out_{t-1} = sigmoid(h_{t-1} @ W_out^T + b) ----
    if (outhead && t > 0 && lr < 12) {
#pragma unroll
        for (int r = 0; r < 4; ++r) {
            const int row = r0 + quad * 4 + r;
            dout[(size_t)row * (NT * NI) + (t - 1) * NI + lr] =
                1.f / (1.f + __expf(-acc[8][r]));
        }
    }
#undef LOAD_STAGE
#undef STORE_STAGE
}

// ---------------------------------------------------------------------------
// heads1: mean / stddev / z from final encoder states (fp32 exact).
// grid 128: block = 16 batch rows x 16 z-dims; thread = one (b, zi).
// ---------------------------------------------------------------------------
__global__ __launch_bounds__(256) void heads1_kernel(
    const float* __restrict__ hf, const float* __restrict__ hb,
    const float* __restrict__ Wmu, const float* __restrict__ bmu,
    const float* __restrict__ Wvar, const float* __restrict__ bvar,
    const float* __restrict__ noise,
    float* __restrict__ dout, float* __restrict__ z32, f16* __restrict__ z16)
{
    const int tid = threadIdx.x;
    const int b  = ((int)blockIdx.x >> 3) * 16 + (tid >> 4);
    const int zi = ((int)blockIdx.x & 7) * 16 + (tid & 15);
    const float4* h4 = (const float4*)(hf + (size_t)b * NH);
    const float4* g4 = (const float4*)(hb + (size_t)b * NH);
    const float4* m4 = (const float4*)(Wmu + (size_t)zi * (2 * NH));
    const float4* v4 = (const float4*)(Wvar + (size_t)zi * (2 * NH));
    float sm_ = 0.f, sv = 0.f;
    for (int k = 0; k < NH / 4; ++k) {
        const float4 h = h4[k], a = m4[k], c = v4[k];
        sm_ += h.x * a.x + h.y * a.y + h.z * a.z + h.w * a.w;
        sv  += h.x * c.x + h.y * c.y + h.z * c.z + h.w * c.w;
    }
    for (int k = 0; k < NH / 4; ++k) {
        const float4 h = g4[k], a = m4[NH / 4 + k], c = v4[NH / 4 + k];
        sm_ += h.x * a.x + h.y * a.y + h.z * a.z + h.w * a.w;
        sv  += h.x * c.x + h.y * c.y + h.z * c.z + h.w * c.w;
    }
    const float mean = sm_ + bmu[zi];
    const float lv   = sv + bvar[zi];
    const float sd   = __expf(0.5f * lv);
    const float zv   = mean + sd * noise[(size_t)b * NZ + zi];
    dout[OUT_MEAN + (size_t)b * NZ + zi] = mean;
    dout[OUT_STD  + (size_t)b * NZ + zi] = sd;
    z32[b * NZ + zi] = zv;
    z16[b * NZ + zi] = (f16)zv;
}

// ---------------------------------------------------------------------------
// heads2: h_dec0 = tanh(z @ W_init^T + b_init). grid 64 (16 hidden dims each).
// ---------------------------------------------------------------------------
__global__ __launch_bounds__(256) void heads2_kernel(
    const float* __restrict__ z32, const float* __restrict__ Winit,
    const float* __restrict__ binit,
    float* __restrict__ h32d, f16* __restrict__ h16d)
{
    __shared__ float Wi[16 * NZ];
    __shared__ float bi[16];
    const int tid = threadIdx.x;
    const int jb = blockIdx.x;
    for (int f = tid; f < 16 * NZ; f += 256)
        Wi[f] = Winit[(size_t)(jb * 16 + (f >> 7)) * NZ + (f & 127)];
    if (tid < 16) bi[tid] = binit[jb * 16 + tid];
    __syncthreads();
    const int b = tid;
    const float4* z4 = (const float4*)(z32 + (size_t)b * NZ);
    float4 zr[NZ / 4];
#pragma unroll
    for (int k = 0; k < NZ / 4; ++k) zr[k] = z4[k];
    for (int hj = 0; hj < 16; ++hj) {
        const float4* w4 = (const float4*)(Wi + hj * NZ);
        float s = bi[hj];
#pragma unroll
        for (int k = 0; k < NZ / 4; ++k) {
            const float4 a = w4[k], z = zr[k];
            s += z.x * a.x + z.y * a.y + z.z * a.z + z.w * a.w;
        }
        const float e2 = __expf(2.f * s);
        const float th = 1.f - 2.f / (e2 + 1.f);
        h32d[(size_t)b * NH + jb * 16 + hj] = th;
        h16d[(size_t)b * NH + jb * 16 + hj] = (f16)th;
    }
}

// ---------------------------------------------------------------------------
extern "C" void kernel_launch(void* const* d_in, const int* in_sizes, int n_in,
                              void* d_out, int out_size, void* d_ws, size_t ws_size,
                              hipStream_t stream)
{
    const float* x     = (const float*)d_in[0];
    const float* noise = (const float*)d_in[1];
    const float* Wihf  = (const float*)d_in[2];
    const float* Whhf  = (const float*)d_in[3];
    const float* bihf  = (const float*)d_in[4];
    const float* bhhf  = (const float*)d_in[5];
    const float* Wihb  = (const float*)d_in[6];
    const float* Whhb  = (const float*)d_in[7];
    const float* bihb  = (const float*)d_in[8];
    const float* bhhb  = (const float*)d_in[9];
    const float* Wmu   = (const float*)d_in[10];
    const float* bmu   = (const float*)d_in[11];
    const float* Wvar  = (const float*)d_in[12];
    const float* bvar  = (const float*)d_in[13];
    const float* Winit = (const float*)d_in[14];
    const float* binit = (const float*)d_in[15];
    const float* Wo    = (const float*)d_in[16];
    const float* bo    = (const float*)d_in[17];
    const float* Wcih  = (const float*)d_in[18];
    const float* Wchh  = (const float*)d_in[19];
    const float* bcih  = (const float*)d_in[20];
    const float* bchh  = (const float*)d_in[21];
    float* dout = (float*)d_out;
    char*  ws   = (char*)d_ws;

    if (ws_size < WS_NEEDED) return;  // ~29 MB required

    f16* wmf  = (f16*)(ws + OFF_WMF);
    f16* wmb  = (f16*)(ws + OFF_WMB);
    f16* wmd  = (f16*)(ws + OFF_WMD);
    f16* wnf  = (f16*)(ws + OFF_WNF);
    f16* wnb  = (f16*)(ws + OFF_WNB);
    f16* wnd  = (f16*)(ws + OFF_WND);
    f16* wo16 = (f16*)(ws + OFF_WOUT);
    float* h32[6]; f16* h16[6];   // f0,f1,b0,b1,d0,d1
    for (int i = 0; i < 6; ++i) {
        h32[i] = (float*)(ws + OFF_H32 + (size_t)i * SZ_H32);
        h16[i] = (f16*)(ws + OFF_H16 + (size_t)i * SZ_H16);
    }
    float* z32p = (float*)(ws + OFF_Z32);
    f16*   z16p = (f16*)(ws + OFF_Z16);

    prep_kernel<<<2048, 256, 0, stream>>>(
        Whhf, Wihf, bihf, bhhf, Whhb, Wihb, bihb, bhhb,
        Wchh, Wcih, bcih, bchh, Wo, bo,
        wmf, wmb, wmd, wnf, wnb, wnd, wo16,
        h32[0], h32[2], h16[0], h16[2]);

    const size_t lds_enc = (size_t)(2 * 96 * 72 + 144 * 40 + 64 * (XK_ENC + 8)) * 2;
    const size_t lds_dec = (size_t)(2 * 96 * 72 + 144 * 40 + 64 * (XK_DEC + 8)) * 2;

    // encoder: 512 steps, both directions per launch (ping-pong h buffers)
    for (int t = 0; t < NT; ++t) {
        const int ia = t & 1, ib = ia ^ 1;
        gru_step<<<256, 256, lds_enc, stream>>>(x,
            wmf, wnf, h16[0 + ia], h32[0 + ia], h16[0 + ib], h32[0 + ib],
            wmb, wnb, h16[2 + ia], h32[2 + ia], h16[2 + ib], h32[2 + ib],
            wo16, z16p, dout, t, 0, KE_ENC, XK_ENC);
    }
    // final encoder states are in buffer 0 (T even)
    heads1_kernel<<<128, 256, 0, stream>>>(h32[0], h32[2], Wmu, bmu, Wvar, bvar,
                                           noise, dout, z32p, z16p);
    heads2_kernel<<<64, 256, 0, stream>>>(z32p, Winit, binit, h32[4], h16[4]);

    // decoder: 512 steps; step t also writes out_{t-1}
    for (int t = 0; t < NT; ++t) {
        const int ia = 4 + (t & 1), ib = 4 + ((t & 1) ^ 1);
        gru_step<<<128, 256, lds_dec, stream>>>(x,
            wmd, wnd, h16[ia], h32[ia], h16[ib], h32[ib],
            wmd, wnd, h16[ia], h32[ia], h16[ib], h32[ib],
            wo16, z16p, dout, t, 1, KE_DEC, XK_DEC);
    }
    // tail: out_511 from h_511 (buffer 4)
    gru_step<<<4, 256, lds_dec, stream>>>(x,
        wmd, wnd, h16[4], h32[4], h16[5], h32[5],
        wmd, wnd, h16[4], h32[4], h16[5], h32[5],
        wo16, z16p, dout, NT, 2, KE_DEC, XK_DEC);
}